// Round 4
// baseline (260.878 us; speedup 1.0000x reference)
//
#include <hip/hip_runtime.h>

typedef __attribute__((ext_vector_type(8))) unsigned short ushort8;
typedef __attribute__((ext_vector_type(8))) short short8;
typedef __attribute__((ext_vector_type(16))) float f32x16;

#define M_DIM 8192
#define N_DIM 2048
#define K_DIM 2048
#define BM 256
#define BN 256
#define BK 64
#define NT (K_DIM / BK)   // 32 k-tiles

// ---- fp32 -> bf16 (RNE) ----
__device__ __forceinline__ unsigned short f32_to_bf16(float f) {
  unsigned int u = __float_as_uint(f);
  u += 0x7fffu + ((u >> 16) & 1u);
  return (unsigned short)(u >> 16);
}

__global__ void __launch_bounds__(256) cast_both_x8(
    const float* __restrict__ x, const float* __restrict__ W,
    unsigned short* __restrict__ xb, unsigned short* __restrict__ Wb) {
  const long nx = (long)M_DIM * K_DIM;
  long i = ((long)blockIdx.x * 256 + threadIdx.x) * 8;
  const float* s;
  unsigned short* d;
  if (i < nx) { s = x + i; d = xb + i; }
  else        { s = W + (i - nx); d = Wb + (i - nx); }
  float4 a = *(const float4*)(s);
  float4 b = *(const float4*)(s + 4);
  ushort8 r;
  r[0] = f32_to_bf16(a.x); r[1] = f32_to_bf16(a.y);
  r[2] = f32_to_bf16(a.z); r[3] = f32_to_bf16(a.w);
  r[4] = f32_to_bf16(b.x); r[5] = f32_to_bf16(b.y);
  r[6] = f32_to_bf16(b.z); r[7] = f32_to_bf16(b.w);
  *(ushort8*)(d) = r;
}

__device__ __forceinline__ void gload_lds16(const unsigned short* g, unsigned short* l) {
  __builtin_amdgcn_global_load_lds(
      (const __attribute__((address_space(1))) void*)g,
      (__attribute__((address_space(3))) void*)l,
      16, 0, 0);
}

// 256x256 pipelined GEMM: C = A(MxK)*B(NxK)^T + bias.  Round-4 structure:
//  - 32x32x16 MFMA (half the instructions of 16x16x32; 13% lower FLOP floor)
//  - ds_reads issued ONE PHASE AHEAD of consumption; NO manual lgkmcnt(0) --
//    the compiler's fine-grained lgkmcnt(N) waits only on the consumed frags,
//    so LDS-read drain overlaps MFMA execution instead of serializing.
//  - 2 barriers per K-tile (was 8): #1 after q2 (buf free for staging),
//    #2 after counted vmcnt(8) in q3 (next buf landed for all waves).
//  - LDS image, chunk-XOR swizzle, staging, A-resident XCD map: round-2 proven.
__global__ void __launch_bounds__(512, 2) gemm_pipe(
    const unsigned short* __restrict__ A,
    const unsigned short* __restrict__ B,
    const float* __restrict__ bias,
    float* __restrict__ C) {
  __shared__ unsigned short lds[2 * 32768];   // [buf][A 16384 | B 16384] elems

  const int tid  = threadIdx.x;
  const int lane = tid & 63;
  const int wave = tid >> 6;
  const int wm   = wave & 1;     // m-half (2)  -> wave owns 128 rows
  const int wn   = wave >> 1;    // n-quarter (4) -> wave owns 64 cols

  // Bijective A-resident remap: 256 blocks = 32 m-tiles x 8 n-tiles.
  const int blk = blockIdx.x;
  const int xcd = blk & 7;
  const int bi  = blk >> 3;
  const int bm0 = (xcd * 4 + (bi & 3)) * BM;
  const int bn0 = (bi >> 2) * BN;

  // staging geometry (round-2): thread loads 4 A + 4 B chunks (16B each).
  // LDS dest linear; source chunk pre-swizzled: cg = cb ^ (row&7).
  const int r0 = tid >> 3;
  const int cg = (tid & 7) ^ (r0 & 7);
  const unsigned short* Ag = A + (size_t)(bm0 + r0) * K_DIM + cg * 8;
  const unsigned short* Bg = B + (size_t)(bn0 + r0) * K_DIM + cg * 8;
  unsigned short* l0 = lds + tid * 8;

#define STAGE(c, t)                                                            \
  do {                                                                         \
    unsigned short* la = l0 + (c) * 32768;                                     \
    const unsigned short* ga = Ag + (t) * BK;                                  \
    const unsigned short* gb = Bg + (t) * BK;                                  \
    _Pragma("unroll")                                                          \
    for (int j = 0; j < 4; ++j) gload_lds16(ga + j * (64 * K_DIM), la + j * 4096); \
    _Pragma("unroll")                                                          \
    for (int j = 0; j < 4; ++j) gload_lds16(gb + j * (64 * K_DIM), la + 16384 + j * 4096); \
  } while (0)

  // 32x32x16 fragment offsets. A-frag: row = lane&31, k = (lane>>5)*8 + j
  // within the K=16 step. Element (row, kchunk) lives at row*64 + chunk*8
  // where chunk = kchunk ^ (row&7). k-step ks changes chunk by XOR (ks<<1),
  // i.e. element offset by XOR (ks<<4).
  const int ln = lane & 31;
  const int hi = lane >> 5;
  int aoff[4], boff[2];
#pragma unroll
  for (int mi = 0; mi < 4; ++mi) {
    int rr = wm * 128 + mi * 32 + ln;
    aoff[mi] = rr * 64 + ((hi ^ (rr & 7)) * 8);
  }
#pragma unroll
  for (int ni = 0; ni < 2; ++ni) {
    int rr = wn * 64 + ni * 32 + ln;
    boff[ni] = rr * 64 + ((hi ^ (rr & 7)) * 8);
  }

  float bv[2];
#pragma unroll
  for (int ni = 0; ni < 2; ++ni) bv[ni] = bias[bn0 + wn * 64 + ni * 32 + ln];

  f32x16 acc[4][2] = {};
  short8 A0[2][4], A1[2][4], B0v[4], B1v[4];

#define LD(p, o) (*(const short8*)((p) + (o)))
#define SB0() __builtin_amdgcn_sched_barrier(0)
#define MFMA32 __builtin_amdgcn_mfma_f32_32x32x16_bf16

  // prologue: tiles 0 (buf0) and 1 (buf1) in flight; wait tile 0 only.
  STAGE(0, 0);
  STAGE(1, 1);
  asm volatile("s_waitcnt vmcnt(8)" ::: "memory");
  __builtin_amdgcn_s_barrier();
  SB0();
  {  // initial A0/B0 fragments from buf0
    const unsigned short* sa = lds;
    const unsigned short* sb = lds + 16384;
#pragma unroll
    for (int mi = 0; mi < 2; ++mi)
#pragma unroll
      for (int ks = 0; ks < 4; ++ks) A0[mi][ks] = LD(sa, aoff[mi] ^ (ks << 4));
#pragma unroll
    for (int ks = 0; ks < 4; ++ks) B0v[ks] = LD(sb, boff[0] ^ (ks << 4));
  }

#pragma unroll 2
  for (int t = 0; t < NT; ++t) {
    const unsigned short* sa = lds + (t & 1) * 32768;
    const unsigned short* sb = sa + 16384;

    // ---- q0: issue B1 reads; compute A0 x B0 (acc[0..1][0]) ----
#pragma unroll
    for (int ks = 0; ks < 4; ++ks) B1v[ks] = LD(sb, boff[1] ^ (ks << 4));
    __builtin_amdgcn_s_setprio(1);
#pragma unroll
    for (int mi = 0; mi < 2; ++mi)
#pragma unroll
      for (int ks = 0; ks < 4; ++ks)
        acc[mi][0] = MFMA32(A0[mi][ks], B0v[ks], acc[mi][0], 0, 0, 0);
    __builtin_amdgcn_s_setprio(0);

    // ---- q1: issue A1 reads; compute A0 x B1 (acc[0..1][1]) ----
#pragma unroll
    for (int mi = 0; mi < 2; ++mi)
#pragma unroll
      for (int ks = 0; ks < 4; ++ks) A1[mi][ks] = LD(sa, aoff[mi + 2] ^ (ks << 4));
    __builtin_amdgcn_s_setprio(1);
#pragma unroll
    for (int mi = 0; mi < 2; ++mi)
#pragma unroll
      for (int ks = 0; ks < 4; ++ks)
        acc[mi][1] = MFMA32(A0[mi][ks], B1v[ks], acc[mi][1], 0, 0, 0);
    __builtin_amdgcn_s_setprio(0);

    // ---- q2: compute A1 x B0 (acc[2..3][0]) ----
    __builtin_amdgcn_s_setprio(1);
#pragma unroll
    for (int mi = 0; mi < 2; ++mi)
#pragma unroll
      for (int ks = 0; ks < 4; ++ks)
        acc[mi + 2][0] = MFMA32(A1[mi][ks], B0v[ks], acc[mi + 2][0], 0, 0, 0);
    __builtin_amdgcn_s_setprio(0);
    SB0();
    __builtin_amdgcn_s_barrier();   // #1: all waves done reading buf (t&1)
    SB0();

    // ---- q3: stage t+2 into freed buf; counted vmcnt; prefetch next frags;
    //          compute A1 x B1 (acc[2..3][1]) ----
    if (t + 2 < NT) {
      STAGE(t & 1, t + 2);
      SB0();
      asm volatile("s_waitcnt vmcnt(8)" ::: "memory");  // t+1's 8 landed; t+2's in flight
    } else {
      asm volatile("s_waitcnt vmcnt(0)" ::: "memory");  // tail: everything long done
    }
    SB0();
    __builtin_amdgcn_s_barrier();   // #2: buf (t+1)&1 landed for ALL waves
    SB0();
    if (t + 1 < NT) {
      const unsigned short* na = lds + ((t + 1) & 1) * 32768;
      const unsigned short* nb = na + 16384;
#pragma unroll
      for (int mi = 0; mi < 2; ++mi)
#pragma unroll
        for (int ks = 0; ks < 4; ++ks) A0[mi][ks] = LD(na, aoff[mi] ^ (ks << 4));
#pragma unroll
      for (int ks = 0; ks < 4; ++ks) B0v[ks] = LD(nb, boff[0] ^ (ks << 4));
    }
    __builtin_amdgcn_s_setprio(1);
#pragma unroll
    for (int mi = 0; mi < 2; ++mi)
#pragma unroll
      for (int ks = 0; ks < 4; ++ks)
        acc[mi + 2][1] = MFMA32(A1[mi][ks], B1v[ks], acc[mi + 2][1], 0, 0, 0);
    __builtin_amdgcn_s_setprio(0);
  }

  // ---- epilogue: C = acc + bias. 32x32 C/D: col = lane&31,
  //      row = (r&3) + 8*(r>>2) + 4*(lane>>5)  ----
#pragma unroll
  for (int ni = 0; ni < 2; ++ni) {
    const int gcol = bn0 + wn * 64 + ni * 32 + ln;
#pragma unroll
    for (int mi = 0; mi < 4; ++mi) {
      const int gbase = bm0 + wm * 128 + mi * 32 + hi * 4;
#pragma unroll
      for (int r = 0; r < 16; ++r) {
        const int grow = gbase + (r & 3) + (r >> 2) * 8;
        C[(size_t)grow * N_DIM + gcol] = acc[mi][ni][r] + bv[ni];
      }
    }
  }
}

extern "C" void kernel_launch(void* const* d_in, const int* in_sizes, int n_in,
                              void* d_out, int out_size, void* d_ws, size_t ws_size,
                              hipStream_t stream) {
  const float* x = (const float*)d_in[0];
  const float* W = (const float*)d_in[1];
  const float* b = (const float*)d_in[2];
  float* out = (float*)d_out;

  unsigned short* xb = (unsigned short*)d_ws;
  unsigned short* Wb = xb + (size_t)M_DIM * K_DIM;

  const long ntot = (long)M_DIM * K_DIM + (long)N_DIM * K_DIM;
  cast_both_x8<<<(int)(ntot / (256 * 8)), 256, 0, stream>>>(x, W, xb, Wb);

  gemm_pipe<<<256, 512, 0, stream>>>(xb, Wb, b, out);
}

// Round 5
// 189.484 us; speedup vs baseline: 1.3768x; 1.3768x over previous
//
#include <hip/hip_runtime.h>

typedef __attribute__((ext_vector_type(8))) unsigned short ushort8;
typedef __attribute__((ext_vector_type(8))) short short8;
typedef __attribute__((ext_vector_type(4))) float f32x4;

#define M_DIM 8192
#define N_DIM 2048
#define K_DIM 2048
#define BM 256
#define BN 256
#define BK 64
#define NT (K_DIM / BK)   // 32 k-tiles

// ---- fp32 -> bf16 (RNE) ----
__device__ __forceinline__ unsigned short f32_to_bf16(float f) {
  unsigned int u = __float_as_uint(f);
  u += 0x7fffu + ((u >> 16) & 1u);
  return (unsigned short)(u >> 16);
}

__global__ void __launch_bounds__(256) cast_both_x8(
    const float* __restrict__ x, const float* __restrict__ W,
    unsigned short* __restrict__ xb, unsigned short* __restrict__ Wb) {
  const long nx = (long)M_DIM * K_DIM;
  long i = ((long)blockIdx.x * 256 + threadIdx.x) * 8;
  const float* s;
  unsigned short* d;
  if (i < nx) { s = x + i; d = xb + i; }
  else        { s = W + (i - nx); d = Wb + (i - nx); }
  float4 a = *(const float4*)(s);
  float4 b = *(const float4*)(s + 4);
  ushort8 r;
  r[0] = f32_to_bf16(a.x); r[1] = f32_to_bf16(a.y);
  r[2] = f32_to_bf16(a.z); r[3] = f32_to_bf16(a.w);
  r[4] = f32_to_bf16(b.x); r[5] = f32_to_bf16(b.y);
  r[6] = f32_to_bf16(b.z); r[7] = f32_to_bf16(b.w);
  *(ushort8*)(d) = r;
}

__device__ __forceinline__ void gload_lds16(const unsigned short* g, unsigned short* l) {
  __builtin_amdgcn_global_load_lds(
      (const __attribute__((address_space(1))) void*)g,
      (__attribute__((address_space(3))) void*)l,
      16, 0, 0);
}

// 256x256 8-phase GEMM: C = A(MxK)*B(NxK)^T + bias.  Round-5 = round-2 base
// (best verified: 77.9us gemm, 0 bank conflicts) + ONE delta: the 8-gload
// staging burst of phase 3 is spread 2/2/4 across phases 1/2/3 (m201/m196:
// the fine ds_read||G::load||MFMA interleave is the lever; coarse staging
// costs 7-27%). Legality of each placement from the phase read-completion
// order: A rows {0-63,128-191} fully read by q0-close -> staged in q1;
// all B rows by q1-close -> staged in q2+q3; A rows {64-127,192-255} by
// q2-close -> staged in q3. vmcnt(8) placement unchanged from round-2.
__global__ void __launch_bounds__(512, 2) gemm_8ph(
    const unsigned short* __restrict__ A,
    const unsigned short* __restrict__ B,
    const float* __restrict__ bias,
    float* __restrict__ C) {
  __shared__ unsigned short lds[2 * 32768];   // [buf][A 16384 | B 16384] elems

  const int tid  = threadIdx.x;
  const int lane = tid & 63;
  const int wave = tid >> 6;
  const int wm   = wave & 1;     // m-half (2)
  const int wn   = wave >> 1;    // n-quarter (4)

  // Bijective A-resident remap: 256 blocks = 32 m-tiles x 8 n-tiles.
  // xcd = blk&7 owns m-tiles {4x..4x+3}: A 4MB fits its L2; B (8MB) is the
  // only cross-XCD stream and lives in L3.
  const int blk = blockIdx.x;
  const int xcd = blk & 7;
  const int bi  = blk >> 3;
  const int bm0 = (xcd * 4 + (bi & 3)) * BM;
  const int bn0 = (bi >> 2) * BN;

  // staging geometry: thread loads 4 A + 4 B chunks (16B each).
  // LDS dest linear (tid*16B + j*8KB); source chunk pre-swizzled: cg = cb^(r&7).
  // gload batch j covers rows j*64 .. j*64+63 of the panel.
  const int r0 = tid >> 3;
  const int cg = (tid & 7) ^ (r0 & 7);
  const unsigned short* Ag = A + (size_t)(bm0 + r0) * K_DIM + cg * 8;
  const unsigned short* Bg = B + (size_t)(bn0 + r0) * K_DIM + cg * 8;
  unsigned short* l0 = lds + tid * 8;

#define GLA(c, t, j) gload_lds16(Ag + (t) * BK + (j) * (64 * K_DIM), \
                                 l0 + (c) * 32768 + (j) * 4096)
#define GLB(c, t, j) gload_lds16(Bg + (t) * BK + (j) * (64 * K_DIM), \
                                 l0 + (c) * 32768 + 16384 + (j) * 4096)

  // fragment LDS offsets (elements); k-half s=1 is offset ^ 32
  const int frow = lane & 15;
  const int q    = lane >> 4;
  int aoff[8], boff[4];
#pragma unroll
  for (int mi = 0; mi < 8; ++mi) {
    int rr = wm * 128 + mi * 16 + frow;
    aoff[mi] = (rr * 8 + (q ^ (rr & 7))) * 8;
  }
#pragma unroll
  for (int ni = 0; ni < 4; ++ni) {
    int rr = wn * 64 + ni * 16 + frow;
    boff[ni] = (rr * 8 + (q ^ (rr & 7))) * 8;
  }

  const int col16 = frow;
  const int row4  = q * 4;
  float bv[4];
#pragma unroll
  for (int ni = 0; ni < 4; ++ni) bv[ni] = bias[bn0 + wn * 64 + ni * 16 + col16];

  f32x4 acc[8][4] = {};

  // prologue: tiles 0 (buf0) and 1 (buf1) in flight; wait tile 0 only.
#pragma unroll
  for (int j = 0; j < 4; ++j) GLA(0, 0, j);
#pragma unroll
  for (int j = 0; j < 4; ++j) GLB(0, 0, j);
#pragma unroll
  for (int j = 0; j < 4; ++j) GLA(1, 1, j);
#pragma unroll
  for (int j = 0; j < 4; ++j) GLB(1, 1, j);
  asm volatile("s_waitcnt vmcnt(8)" ::: "memory");
  __builtin_amdgcn_s_barrier();

#define PH_OPEN()                                        \
    __builtin_amdgcn_s_barrier();                        \
    asm volatile("s_waitcnt lgkmcnt(0)" ::: "memory");   \
    __builtin_amdgcn_sched_barrier(0);                   \
    __builtin_amdgcn_s_setprio(1)
#define PH_CLOSE()                                       \
    __builtin_amdgcn_s_setprio(0);                       \
    __builtin_amdgcn_sched_barrier(0);                   \
    __builtin_amdgcn_s_barrier()
#define LDA(o) (*(const short8*)(sa + (o)))
#define LDB(o) (*(const short8*)(sb + (o)))

#pragma unroll 2
  for (int t = 0; t < NT; ++t) {
    const unsigned short* sa = lds + (t & 1) * 32768;
    const unsigned short* sb = sa + 16384;
    short8 a[4][2], b01[2][2], b23[2][2];
    const bool pf = (t + 2 < NT);
    const int  sc = t & 1;           // staging target buf (freed region-wise)

    // ---------- phase 0 : (m 0-63) x (n 0-31) : 12 ds_reads ----------
#pragma unroll
    for (int mi = 0; mi < 4; ++mi) { a[mi][0] = LDA(aoff[mi]); a[mi][1] = LDA(aoff[mi] ^ 32); }
#pragma unroll
    for (int ni = 0; ni < 2; ++ni) { b01[ni][0] = LDB(boff[ni]); b01[ni][1] = LDB(boff[ni] ^ 32); }
    PH_OPEN();
#pragma unroll
    for (int mi = 0; mi < 4; ++mi)
#pragma unroll
      for (int ni = 0; ni < 2; ++ni)
#pragma unroll
        for (int s = 0; s < 2; ++s)
          acc[mi][ni] = __builtin_amdgcn_mfma_f32_16x16x32_bf16(
              a[mi][s], b01[ni][s], acc[mi][ni], 0, 0, 0);
    PH_CLOSE();

    // ---- phase 1 : (m 0-63) x (n 32-63) : 4 ds_reads + stage A j=0,2 ----
    // (A rows 0-63 / 128-191 were fully read before q0's closing barrier.)
#pragma unroll
    for (int ni = 0; ni < 2; ++ni) { b23[ni][0] = LDB(boff[ni + 2]); b23[ni][1] = LDB(boff[ni + 2] ^ 32); }
    if (pf) { GLA(sc, t + 2, 0); GLA(sc, t + 2, 2); }
    PH_OPEN();
#pragma unroll
    for (int mi = 0; mi < 4; ++mi)
#pragma unroll
      for (int ni = 0; ni < 2; ++ni)
#pragma unroll
        for (int s = 0; s < 2; ++s)
          acc[mi][ni + 2] = __builtin_amdgcn_mfma_f32_16x16x32_bf16(
              a[mi][s], b23[ni][s], acc[mi][ni + 2], 0, 0, 0);
    PH_CLOSE();

    // ---- phase 2 : (m 64-127) x (n 0-31) : 8 ds_reads + stage B j=0,1 ----
    // (all B rows were fully read before q1's closing barrier.)
#pragma unroll
    for (int mi = 0; mi < 4; ++mi) { a[mi][0] = LDA(aoff[mi + 4]); a[mi][1] = LDA(aoff[mi + 4] ^ 32); }
    if (pf) { GLB(sc, t + 2, 0); GLB(sc, t + 2, 1); }
    PH_OPEN();
#pragma unroll
    for (int mi = 0; mi < 4; ++mi)
#pragma unroll
      for (int ni = 0; ni < 2; ++ni)
#pragma unroll
        for (int s = 0; s < 2; ++s)
          acc[mi + 4][ni] = __builtin_amdgcn_mfma_f32_16x16x32_bf16(
              a[mi][s], b01[ni][s], acc[mi + 4][ni], 0, 0, 0);
    PH_CLOSE();

    // ---- phase 3 : (m 64-127) x (n 32-63) + stage B j=2,3, A j=1,3 ----
    // (A rows 64-127 / 192-255 were fully read before q2's closing barrier.)
    // Counted vmcnt(8) AFTER the MFMAs: t+1's 8 loads (issued during t-1)
    // have landed; t+2's 8 stay in flight across the tile boundary.
    if (pf) { GLB(sc, t + 2, 2); GLB(sc, t + 2, 3); GLA(sc, t + 2, 1); GLA(sc, t + 2, 3); }
    __builtin_amdgcn_sched_barrier(0);
    __builtin_amdgcn_s_setprio(1);
#pragma unroll
    for (int mi = 0; mi < 4; ++mi)
#pragma unroll
      for (int ni = 0; ni < 2; ++ni)
#pragma unroll
        for (int s = 0; s < 2; ++s)
          acc[mi + 4][ni + 2] = __builtin_amdgcn_mfma_f32_16x16x32_bf16(
              a[mi][s], b23[ni][s], acc[mi + 4][ni + 2], 0, 0, 0);
    __builtin_amdgcn_s_setprio(0);
    __builtin_amdgcn_sched_barrier(0);
    if (pf)
      asm volatile("s_waitcnt vmcnt(8)" ::: "memory");
    else
      asm volatile("s_waitcnt vmcnt(0)" ::: "memory");
    __builtin_amdgcn_s_barrier();
  }

  // ---------------- epilogue: C = acc + bias ----------------
#pragma unroll
  for (int ni = 0; ni < 4; ++ni) {
    const int gcol = bn0 + wn * 64 + ni * 16 + col16;
#pragma unroll
    for (int mi = 0; mi < 8; ++mi) {
      const int grow = bm0 + wm * 128 + mi * 16 + row4;
#pragma unroll
      for (int r = 0; r < 4; ++r)
        C[(size_t)(grow + r) * N_DIM + gcol] = acc[mi][ni][r] + bv[ni];
    }
  }
}

extern "C" void kernel_launch(void* const* d_in, const int* in_sizes, int n_in,
                              void* d_out, int out_size, void* d_ws, size_t ws_size,
                              hipStream_t stream) {
  const float* x = (const float*)d_in[0];
  const float* W = (const float*)d_in[1];
  const float* b = (const float*)d_in[2];
  float* out = (float*)d_out;

  unsigned short* xb = (unsigned short*)d_ws;
  unsigned short* Wb = xb + (size_t)M_DIM * K_DIM;

  const long ntot = (long)M_DIM * K_DIM + (long)N_DIM * K_DIM;
  cast_both_x8<<<(int)(ntot / (256 * 8)), 256, 0, stream>>>(x, W, xb, Wb);

  gemm_8ph<<<256, 512, 0, stream>>>(xb, Wb, b, out);
}